// Round 5
// baseline (347.208 us; speedup 1.0000x reference)
//
#include <hip/hip_runtime.h>

// Problem constants (B,S,D_IN,D_HID,D_OUT) = (8,4096,512,1024,512)
#define B_    8
#define S_    4096
#define DIN   512
#define DHID  1024
#define DOUT  512
#define M_    (B_*S_)          // 32768
#define NCAT  (DHID + DOUT)    // 1536
#define CH2   32
#define NCH2  (S_/CH2)         // 128

typedef __bf16 bf16x8 __attribute__((ext_vector_type(8)));
typedef float  floatx4 __attribute__((ext_vector_type(4)));

__device__ __forceinline__ unsigned short f2bf(float f) {
  unsigned u = __builtin_bit_cast(unsigned, f);
  u = (u + 0x7FFFu + ((u >> 16) & 1u)) >> 16;   // RNE
  return (unsigned short)u;
}
__device__ __forceinline__ float bf2f(unsigned short h) {
  unsigned u = ((unsigned)h) << 16;
  return __builtin_bit_cast(float, u);
}

__device__ __forceinline__ void gl_lds16(const unsigned short* g, unsigned short* l) {
  __builtin_amdgcn_global_load_lds((const __attribute__((address_space(1))) void*)g,
                                   (__attribute__((address_space(3))) void*)l, 16, 0, 0);
}

// ---------- fused prep: wcat (3072 blk) | woutt (2048 blk) | a_s (4 blk) ----------
__global__ void prep_all(const float* __restrict__ logit,
                         const float* __restrict__ Win, const float* __restrict__ Wdx,
                         const float* __restrict__ Wout,
                         float* __restrict__ a_s,
                         unsigned short* __restrict__ wcat,
                         unsigned short* __restrict__ woutt) {
  int bx = blockIdx.x;
  if (bx < 3072) {                       // Wcat^T: n in [0,1536), k in [0,512)
    int idx = bx * 256 + threadIdx.x;
    int n = idx >> 9, k = idx & 511;
    float v = (n < DHID) ? Win[(size_t)k * DHID + n] : Wdx[(size_t)k * DOUT + (n - DHID)];
    wcat[idx] = f2bf(v);
  } else if (bx < 5120) {                // Wout^T: n in [0,512), k in [0,1024)
    int idx = (bx - 3072) * 256 + threadIdx.x;
    int n = idx >> 10, k = idx & 1023;
    woutt[idx] = f2bf(Wout[(size_t)k * DOUT + n]);
  } else {                               // a_s
    int d = (bx - 5120) * 256 + threadIdx.x;
    if (d < DHID) {
      float a = 1.f / (1.f + expf(-logit[d]));
      a_s[d] = a;
      a_s[DHID + d] = sqrtf(fmaxf(1.f - a * a, 0.f));
    }
  }
}

// ---------- GEMM (128x128 tile, 4 waves of 64x64, mfma 16x16x32 bf16) ----------
// A staged via registers (+1-iter prefetch to hide HBM latency under MFMA);
// MODE 0 converts fp32 x -> bf16 in-flight (prep_x fused). B via global_load_lds
// (L2-resident). XOR-8 colblock swizzle on both paths; XCD-aware block swizzle.
// MODE 0: C = x(MxK fp32) * Wcat^T; n<1024: u=(c+b_in)*s bf16 ; n>=1024: dx=c+b_dx bf16
// MODE 1: C = h(MxK bf16) * Wout^T; out = (c + b_out + dx)*0.5 fp32
template <int K, int MODE, int NB>
__global__ __launch_bounds__(256, 3) void gemm_bt(
    const float* __restrict__ Af,            // MODE0 A (fp32)
    const unsigned short* __restrict__ Ab,   // MODE1 A (bf16)
    const unsigned short* __restrict__ Bt,
    const float* __restrict__ a_s,
    const float* __restrict__ bias0,
    const float* __restrict__ bias1,
    unsigned short* __restrict__ u_out,
    unsigned short* __restrict__ dx_buf,
    float* __restrict__ out)
{
  __shared__ __align__(16) unsigned char smem[32768];
  unsigned short* lA = (unsigned short*)smem;            // 128 x 64 bf16
  unsigned short* lB = (unsigned short*)(smem + 16384);  // 128 x 64 bf16
  float* stg = (float*)smem;                             // epilogue stage, 32 x 132 fp32

  const int tid = threadIdx.x;
  const int flat = blockIdx.y * gridDim.x + blockIdx.x;
  const int xcd = flat & 7;
  const int j = flat >> 3;
  const int n0 = (j % NB) * 128;
  const int m0 = ((j / NB) * 8 + xcd) * 128;

  const int wid = tid >> 6, lane = tid & 63;
  const int wm = (wid >> 1) * 64, wn = (wid & 1) * 64;
  const int r16 = lane & 15, quad = lane >> 4;
  const int sw = r16 & 7;

  const int rsub = lane >> 3;                 // row within 8-row staging group
  const int gcol = ((lane & 7) ^ rsub) << 3;  // swizzled source col block

  const int arow = (wid << 5) + rsub;         // A/B staging row base (this wave)
  const unsigned short* Bbase = Bt + (size_t)(n0 + arow) * K + gcol;
  unsigned short* lBw = lB + (wid << 5) * 64;
  // A LDS store addr: row (wid*32 + i*8 + rsub), cols (lane&7)*8 (data from gcol)
  unsigned short* lAst = lA + ((wid << 5) + rsub) * 64 + (lane & 7) * 8;

  floatx4 acc[4][4] = {};
  bf16x8 apre[4];

  // A-slice register load (independent vmem; conversion for MODE0)
  auto loadA = [&](int k0) {
#pragma unroll
    for (int i = 0; i < 4; ++i) {
      if (MODE == 0) {
        const float* src = Af + (size_t)(m0 + arow + i * 8) * K + k0 + gcol;
        float4 f0 = *(const float4*)src;
        float4 f1 = *(const float4*)(src + 4);
        union { unsigned short s[8]; bf16x8 v; } t;
        t.s[0] = f2bf(f0.x); t.s[1] = f2bf(f0.y); t.s[2] = f2bf(f0.z); t.s[3] = f2bf(f0.w);
        t.s[4] = f2bf(f1.x); t.s[5] = f2bf(f1.y); t.s[6] = f2bf(f1.z); t.s[7] = f2bf(f1.w);
        apre[i] = t.v;
      } else {
        apre[i] = *(const bf16x8*)(Ab + (size_t)(m0 + arow + i * 8) * K + k0 + gcol);
      }
    }
  };

  loadA(0);
  for (int k0 = 0; k0 < K; k0 += 64) {
#pragma unroll
    for (int i = 0; i < 4; ++i)
      *(bf16x8*)(lAst + i * 8 * 64) = apre[i];
#pragma unroll
    for (int i = 0; i < 4; ++i)
      gl_lds16(Bbase + (size_t)(i * 8) * K + k0, lBw + i * 8 * 64);
    __syncthreads();
    if (k0 + 64 < K) loadA(k0 + 64);   // prefetch overlaps MFMA below
#pragma unroll
    for (int ks = 0; ks < 2; ++ks) {
      bf16x8 af[4], bfr[4];
#pragma unroll
      for (int i = 0; i < 4; ++i)
        af[i] = *(const bf16x8*)&lA[(wm + i * 16 + r16) * 64 + ((((ks << 2) | quad) ^ sw) << 3)];
#pragma unroll
      for (int j2 = 0; j2 < 4; ++j2)
        bfr[j2] = *(const bf16x8*)&lB[(wn + j2 * 16 + r16) * 64 + ((((ks << 2) | quad) ^ sw) << 3)];
#pragma unroll
      for (int i = 0; i < 4; ++i)
#pragma unroll
        for (int j2 = 0; j2 < 4; ++j2)
          acc[i][j2] = __builtin_amdgcn_mfma_f32_16x16x32_bf16(af[i], bfr[j2], acc[i][j2], 0, 0, 0);
    }
    __syncthreads();
  }

  // ---- epilogue: 4 passes of 32 rows through LDS (fp32, stride 132), coalesced stores ----
  const int row = tid >> 3;   // 0..31
  const int seg = tid & 7;    // 0..7
#pragma unroll
  for (int p = 0; p < 4; ++p) {
    __syncthreads();
    if ((wid >> 1) == (p >> 1)) {
      const int i0 = (p & 1) * 2;
#pragma unroll
      for (int ii = 0; ii < 2; ++ii) {
        const int i = i0 + ii;
        const int srow = i * 16 + quad * 4 - (p & 1) * 32;
#pragma unroll
        for (int j2 = 0; j2 < 4; ++j2) {
          const int scol = wn + j2 * 16 + r16;
#pragma unroll
          for (int r = 0; r < 4; ++r)
            stg[(srow + r) * 132 + scol] = acc[i][j2][r];
        }
      }
    }
    __syncthreads();
    const int gm = m0 + p * 32 + row;
    const int col0 = n0 + seg * 16;
    if (MODE == 0) {
      union { unsigned short s[16]; uint4 q[2]; } ub;
      if (n0 < DHID) {
#pragma unroll
        for (int u = 0; u < 4; ++u) {
          float4 v  = *(const float4*)&stg[row * 132 + seg * 16 + u * 4];
          float4 bi = *(const float4*)&bias0[col0 + u * 4];
          float4 sc = *(const float4*)&a_s[DHID + col0 + u * 4];
          ub.s[u * 4 + 0] = f2bf((v.x + bi.x) * sc.x);
          ub.s[u * 4 + 1] = f2bf((v.y + bi.y) * sc.y);
          ub.s[u * 4 + 2] = f2bf((v.z + bi.z) * sc.z);
          ub.s[u * 4 + 3] = f2bf((v.w + bi.w) * sc.w);
        }
        *(uint4*)&u_out[(size_t)gm * DHID + col0]     = ub.q[0];
        *(uint4*)&u_out[(size_t)gm * DHID + col0 + 8] = ub.q[1];
      } else {
        const int c2 = col0 - DHID;
#pragma unroll
        for (int u = 0; u < 4; ++u) {
          float4 v  = *(const float4*)&stg[row * 132 + seg * 16 + u * 4];
          float4 bd = *(const float4*)&bias1[c2 + u * 4];
          ub.s[u * 4 + 0] = f2bf(v.x + bd.x);
          ub.s[u * 4 + 1] = f2bf(v.y + bd.y);
          ub.s[u * 4 + 2] = f2bf(v.z + bd.z);
          ub.s[u * 4 + 3] = f2bf(v.w + bd.w);
        }
        *(uint4*)&dx_buf[(size_t)gm * DOUT + c2]     = ub.q[0];
        *(uint4*)&dx_buf[(size_t)gm * DOUT + c2 + 8] = ub.q[1];
      }
    } else {
#pragma unroll
      for (int u = 0; u < 4; ++u) {
        float4 v  = *(const float4*)&stg[row * 132 + seg * 16 + u * 4];
        float4 bo = *(const float4*)&bias0[col0 + u * 4];
        ushort4 dv = *(const ushort4*)&dx_buf[(size_t)gm * DOUT + col0 + u * 4];
        float4 o;
        o.x = (v.x + bo.x + bf2f(dv.x)) * 0.5f;
        o.y = (v.y + bo.y + bf2f(dv.y)) * 0.5f;
        o.z = (v.z + bo.z + bf2f(dv.z)) * 0.5f;
        o.w = (v.w + bo.w + bf2f(dv.w)) * 0.5f;
        *(float4*)&out[(size_t)gm * DOUT + col0 + u * 4] = o;
      }
    }
  }
}

// ---------- scan kernels: 8 d's per thread, 16 B/lane fully-coalesced ----------
__global__ __launch_bounds__(256) void scan1(const unsigned short* __restrict__ u,
                                             const float* __restrict__ a_s,
                                             float* __restrict__ carry) {
  int idx = blockIdx.x * 256 + threadIdx.x;       // B*NCH2*(DHID/8) = 131072
  int d8 = (idx & 127) * 8;
  int c  = (idx >> 7) & (NCH2 - 1);
  int b  = idx >> 14;
  float4 a0 = *(const float4*)&a_s[d8];
  float4 a1 = *(const float4*)&a_s[d8 + 4];
  float h0_ = 0.f, h1 = 0.f, h2 = 0.f, h3 = 0.f, h4 = 0.f, h5 = 0.f, h6 = 0.f, h7 = 0.f;
  const unsigned short* up = u + ((size_t)(b * S_ + c * CH2)) * DHID + d8;
#pragma unroll 4
  for (int t = 0; t < CH2; ++t) {
    ushort4 q0 = *(const ushort4*)up;
    ushort4 q1 = *(const ushort4*)(up + 4);
    h0_ = fmaf(a0.x, h0_, bf2f(q0.x)); h1 = fmaf(a0.y, h1, bf2f(q0.y));
    h2  = fmaf(a0.z, h2,  bf2f(q0.z)); h3 = fmaf(a0.w, h3, bf2f(q0.w));
    h4  = fmaf(a1.x, h4,  bf2f(q1.x)); h5 = fmaf(a1.y, h5, bf2f(q1.y));
    h6  = fmaf(a1.z, h6,  bf2f(q1.z)); h7 = fmaf(a1.w, h7, bf2f(q1.w));
    up += DHID;
  }
  float* cp = &carry[((size_t)(b * NCH2 + c)) * DHID + d8];
  float4 o0 = {h0_, h1, h2, h3}, o1 = {h4, h5, h6, h7};
  *(float4*)cp = o0;
  *(float4*)(cp + 4) = o1;
}

// pass 1.5: sequential prefix over chunks with 8-deep load batching; writes h_last.
__global__ __launch_bounds__(256) void scan_mid(const float* __restrict__ a_s,
                                                const float* __restrict__ h0,
                                                float* __restrict__ carry,
                                                float* __restrict__ h_last) {
  int idx = blockIdx.x * 256 + threadIdx.x;   // B_*DHID = 8192
  int d = idx & (DHID - 1);
  int b = idx >> 10;
  float a = a_s[d];
  float aL = a;
#pragma unroll
  for (int q = 0; q < 5; ++q) aL *= aL;       // a^32
  float st = h0[(size_t)b * DHID + d];
  float* p = &carry[(size_t)b * NCH2 * DHID + d];
  for (int cg = 0; cg < NCH2; cg += 8) {
    float loc[8];
#pragma unroll
    for (int j = 0; j < 8; ++j) loc[j] = p[(size_t)j * DHID];
#pragma unroll
    for (int j = 0; j < 8; ++j) {
      p[(size_t)j * DHID] = st;
      st = fmaf(aL, st, loc[j]);
    }
    p += (size_t)8 * DHID;
  }
  h_last[(size_t)b * DHID + d] = st;
}

// pass 2: recompute scan from exact entry state; overwrite u with h (bf16)
__global__ __launch_bounds__(256) void scan2(unsigned short* __restrict__ u,
                                             const float* __restrict__ a_s,
                                             const float* __restrict__ carry) {
  int idx = blockIdx.x * 256 + threadIdx.x;
  int d8 = (idx & 127) * 8;
  int c  = (idx >> 7) & (NCH2 - 1);
  int b  = idx >> 14;
  float4 a0 = *(const float4*)&a_s[d8];
  float4 a1 = *(const float4*)&a_s[d8 + 4];
  const float* cp = &carry[((size_t)(b * NCH2 + c)) * DHID + d8];
  float4 e0 = *(const float4*)cp;
  float4 e1 = *(const float4*)(cp + 4);
  float h0_ = e0.x, h1 = e0.y, h2 = e0.z, h3 = e0.w;
  float h4 = e1.x, h5 = e1.y, h6 = e1.z, h7 = e1.w;
  unsigned short* up = u + ((size_t)(b * S_ + c * CH2)) * DHID + d8;
#pragma unroll 4
  for (int t = 0; t < CH2; ++t) {
    ushort4 q0 = *(const ushort4*)up;
    ushort4 q1 = *(const ushort4*)(up + 4);
    h0_ = fmaf(a0.x, h0_, bf2f(q0.x)); h1 = fmaf(a0.y, h1, bf2f(q0.y));
    h2  = fmaf(a0.z, h2,  bf2f(q0.z)); h3 = fmaf(a0.w, h3, bf2f(q0.w));
    h4  = fmaf(a1.x, h4,  bf2f(q1.x)); h5 = fmaf(a1.y, h5, bf2f(q1.y));
    h6  = fmaf(a1.z, h6,  bf2f(q1.z)); h7 = fmaf(a1.w, h7, bf2f(q1.w));
    ushort4 w0, w1;
    w0.x = f2bf(h0_); w0.y = f2bf(h1); w0.z = f2bf(h2); w0.w = f2bf(h3);
    w1.x = f2bf(h4);  w1.y = f2bf(h5); w1.z = f2bf(h6); w1.w = f2bf(h7);
    *(ushort4*)up = w0;
    *(ushort4*)(up + 4) = w1;
    up += DHID;
  }
}

extern "C" void kernel_launch(void* const* d_in, const int* in_sizes, int n_in,
                              void* d_out, int out_size, void* d_ws, size_t ws_size,
                              hipStream_t stream) {
  const float* x    = (const float*)d_in[0];
  const float* h0   = (const float*)d_in[1];
  const float* alog = (const float*)d_in[2];
  const float* Wdx  = (const float*)d_in[3];
  const float* bdx  = (const float*)d_in[4];
  const float* Win  = (const float*)d_in[5];
  const float* bin  = (const float*)d_in[6];
  const float* Wout = (const float*)d_in[7];
  const float* bout = (const float*)d_in[8];

  float* out    = (float*)d_out;
  float* h_last = out + (size_t)M_ * DOUT;

  char* ws = (char*)d_ws;
  unsigned short* ubuf  = (unsigned short*)(ws);                      // 64 MB (u -> h in-place)
  unsigned short* dxb   = (unsigned short*)(ws + 67108864ull);        // 32 MB
  unsigned short* wcat  = (unsigned short*)(ws + 100663296ull);       // 1.5 MB
  unsigned short* woutt = (unsigned short*)(ws + 102236160ull);       // 1 MB
  float*          a_s   = (float*)(ws + 103284736ull);                // 8 KB
  float*          carry = (float*)(ws + 103292928ull);                // 4 MB

  prep_all<<<5124, 256, 0, stream>>>(alog, Win, Wdx, Wout, a_s, wcat, woutt);

  // GEMM1 (x fp32 consumed directly): u = (x@W_in + b_in)*s (bf16), dx = x@W_dx + b_dx (bf16)
  gemm_bt<DIN, 0, 12><<<dim3(NCAT / 128, M_ / 128), 256, 0, stream>>>(
      x, nullptr, wcat, a_s, bin, bdx, ubuf, dxb, nullptr);

  // linear scan (chunked, CH2=32)
  scan1   <<<(B_ * NCH2 * (DHID / 8)) / 256, 256, 0, stream>>>(ubuf, a_s, carry);
  scan_mid<<<(B_ * DHID) / 256, 256, 0, stream>>>(a_s, h0, carry, h_last);
  scan2   <<<(B_ * NCH2 * (DHID / 8)) / 256, 256, 0, stream>>>(ubuf, a_s, carry);

  // GEMM2: out = (dx + h@W_out + b_out)/2
  gemm_bt<DHID, 1, 4><<<dim3(DOUT / 128, M_ / 128), 256, 0, stream>>>(
      nullptr, ubuf, woutt, a_s, bout, nullptr, nullptr, dxb, out);
}

// Round 6
// 293.696 us; speedup vs baseline: 1.1822x; 1.1822x over previous
//
#include <hip/hip_runtime.h>

// Problem constants (B,S,D_IN,D_HID,D_OUT) = (8,4096,512,1024,512)
#define B_    8
#define S_    4096
#define DIN   512
#define DHID  1024
#define DOUT  512
#define M_    (B_*S_)          // 32768
#define NCAT  (DHID + DOUT)    // 1536
#define CH2   32
#define NCH2  (S_/CH2)         // 128

typedef __bf16 bf16x8 __attribute__((ext_vector_type(8)));
typedef float  floatx4 __attribute__((ext_vector_type(4)));

__device__ __forceinline__ unsigned short f2bf(float f) {
  unsigned u = __builtin_bit_cast(unsigned, f);
  u = (u + 0x7FFFu + ((u >> 16) & 1u)) >> 16;   // RNE
  return (unsigned short)u;
}
__device__ __forceinline__ float bf2f(unsigned short h) {
  unsigned u = ((unsigned)h) << 16;
  return __builtin_bit_cast(float, u);
}

__device__ __forceinline__ void gl_lds16(const unsigned short* g, unsigned short* l) {
  __builtin_amdgcn_global_load_lds((const __attribute__((address_space(1))) void*)g,
                                   (__attribute__((address_space(3))) void*)l, 16, 0, 0);
}

// ---------- fused prep: wcat | woutt | a_s | x->bf16 (single launch) ----------
__global__ void prep_all(const float* __restrict__ logit,
                         const float* __restrict__ Win, const float* __restrict__ Wdx,
                         const float* __restrict__ Wout, const float* __restrict__ x,
                         float* __restrict__ a_s,
                         unsigned short* __restrict__ wcat,
                         unsigned short* __restrict__ woutt,
                         unsigned short* __restrict__ xb) {
  int bx = blockIdx.x;
  if (bx < 3072) {                       // Wcat^T: n in [0,1536), k in [0,512)
    int idx = bx * 256 + threadIdx.x;
    int n = idx >> 9, k = idx & 511;
    float v = (n < DHID) ? Win[(size_t)k * DHID + n] : Wdx[(size_t)k * DOUT + (n - DHID)];
    wcat[idx] = f2bf(v);
  } else if (bx < 5120) {                // Wout^T: n in [0,512), k in [0,1024)
    int idx = (bx - 3072) * 256 + threadIdx.x;
    int n = idx >> 10, k = idx & 1023;
    woutt[idx] = f2bf(Wout[(size_t)k * DOUT + n]);
  } else if (bx < 5124) {                // a_s
    int d = (bx - 5120) * 256 + threadIdx.x;
    if (d < DHID) {
      float a = 1.f / (1.f + expf(-logit[d]));
      a_s[d] = a;
      a_s[DHID + d] = sqrtf(fmaxf(1.f - a * a, 0.f));
    }
  } else {                               // x fp32 -> bf16, 8 elems/thread
    size_t i = (size_t)(bx - 5124) * 256 + threadIdx.x;
    const float4* p = (const float4*)x;
    float4 v0 = p[i * 2];
    float4 v1 = p[i * 2 + 1];
    uint4 o;
    o.x = (unsigned)f2bf(v0.x) | ((unsigned)f2bf(v0.y) << 16);
    o.y = (unsigned)f2bf(v0.z) | ((unsigned)f2bf(v0.w) << 16);
    o.z = (unsigned)f2bf(v1.x) | ((unsigned)f2bf(v1.y) << 16);
    o.w = (unsigned)f2bf(v1.z) | ((unsigned)f2bf(v1.w) << 16);
    *(uint4*)&xb[i * 8] = o;
  }
}

// ---------- GEMM (128x128 tile, 4 waves of 64x64, mfma 16x16x32 bf16) ----------
// Round-4 proven core: global_load_lds A+B with XOR-8 colblock swizzle, XCD-aware
// block swizzle, __launch_bounds__(256,4).
// MODE 0: C = A(MxK) * Wcat^T; n<1024: u=(c+b_in)*s bf16 (+ fused scan1: per-32-row
//         chunk-local scan final -> carry); n>=1024: dx=c+b_dx bf16
// MODE 1: C = H(MxK) * Wout^T; out = (c + b_out + dx)*0.5 fp32
template <int K, int MODE, int NB>
__global__ __launch_bounds__(256, 4) void gemm_bt(
    const unsigned short* __restrict__ A,
    const unsigned short* __restrict__ Bt,
    const float* __restrict__ a_s,
    const float* __restrict__ bias0,
    const float* __restrict__ bias1,
    unsigned short* __restrict__ u_out,
    unsigned short* __restrict__ dx_buf,
    float* __restrict__ out,
    float* __restrict__ carry)
{
  __shared__ __align__(16) unsigned char smem[32768];
  unsigned short* lA = (unsigned short*)smem;            // 128 x 64 bf16
  unsigned short* lB = (unsigned short*)(smem + 16384);  // 128 x 64 bf16
  float* stg  = (float*)smem;                            // epilogue stage, 32 x 132 fp32
  float* ltmp = (float*)(smem + 16896);                  // 128 floats (scan combine)

  const int tid = threadIdx.x;
  const int flat = blockIdx.y * gridDim.x + blockIdx.x;
  const int xcd = flat & 7;
  const int j = flat >> 3;
  const int n0 = (j % NB) * 128;
  const int m0 = ((j / NB) * 8 + xcd) * 128;

  const int wid = tid >> 6, lane = tid & 63;
  const int wm = (wid >> 1) * 64, wn = (wid & 1) * 64;
  const int r16 = lane & 15, quad = lane >> 4;
  const int sw = r16 & 7;

  const int rsub = lane >> 3;
  const int gcol = ((lane & 7) ^ rsub) << 3;

  const unsigned short* Abase = A + (size_t)(m0 + (wid << 5) + rsub) * K + gcol;
  const unsigned short* Bbase = Bt + (size_t)(n0 + (wid << 5) + rsub) * K + gcol;
  unsigned short* lAw = lA + (wid << 5) * 64;
  unsigned short* lBw = lB + (wid << 5) * 64;

  floatx4 acc[4][4] = {};

  for (int k0 = 0; k0 < K; k0 += 64) {
#pragma unroll
    for (int i = 0; i < 4; ++i) {
      gl_lds16(Abase + (size_t)(i * 8) * K + k0, lAw + i * 8 * 64);
      gl_lds16(Bbase + (size_t)(i * 8) * K + k0, lBw + i * 8 * 64);
    }
    __syncthreads();
#pragma unroll
    for (int ks = 0; ks < 2; ++ks) {
      bf16x8 af[4], bfr[4];
#pragma unroll
      for (int i = 0; i < 4; ++i)
        af[i] = *(const bf16x8*)&lA[(wm + i * 16 + r16) * 64 + ((((ks << 2) | quad) ^ sw) << 3)];
#pragma unroll
      for (int j2 = 0; j2 < 4; ++j2)
        bfr[j2] = *(const bf16x8*)&lB[(wn + j2 * 16 + r16) * 64 + ((((ks << 2) | quad) ^ sw) << 3)];
#pragma unroll
      for (int i = 0; i < 4; ++i)
#pragma unroll
        for (int j2 = 0; j2 < 4; ++j2)
          acc[i][j2] = __builtin_amdgcn_mfma_f32_16x16x32_bf16(af[i], bfr[j2], acc[i][j2], 0, 0, 0);
    }
    __syncthreads();
  }

  // ---- epilogue: 4 passes of 32 rows through LDS (fp32, stride 132) ----
  const int row = tid >> 3;   // 0..31
  const int seg = tid & 7;    // 0..7
  // fused-scan1 per-thread constants (MODE 0, u-blocks only)
  const int scol_ = tid & 127;   // tile column owned for scan
  const int shalf = tid >> 7;    // 0: rows 0-15, 1: rows 16-31
  float aa = 0.f, sbi = 0.f, ssc = 0.f, a16 = 0.f;
  if (MODE == 0 && n0 < DHID) {
    aa  = a_s[n0 + scol_];
    sbi = bias0[n0 + scol_];
    ssc = a_s[DHID + n0 + scol_];
    float t2 = aa * aa, t4 = t2 * t2, t8 = t4 * t4;
    a16 = t8 * t8;
  }
  const int bb = m0 >> 12;               // batch
  const int c0 = (m0 & 4095) >> 5;       // base chunk within batch

#pragma unroll
  for (int p = 0; p < 4; ++p) {
    __syncthreads();
    if ((wid >> 1) == (p >> 1)) {
      const int i0 = (p & 1) * 2;
#pragma unroll
      for (int ii = 0; ii < 2; ++ii) {
        const int i = i0 + ii;
        const int srow = i * 16 + quad * 4 - (p & 1) * 32;
#pragma unroll
        for (int j2 = 0; j2 < 4; ++j2) {
          const int scol = wn + j2 * 16 + r16;
#pragma unroll
          for (int r = 0; r < 4; ++r)
            stg[(srow + r) * 132 + scol] = acc[i][j2][r];
        }
      }
    }
    __syncthreads();

    // fused scan1: chunk-local weighted sum over the 32 rows of this pass
    if (MODE == 0 && n0 < DHID) {
      float P = 0.f;
      const float* sp = &stg[(shalf * 16) * 132 + scol_];
#pragma unroll
      for (int r = 0; r < 16; ++r) {
        P = fmaf(aa, P, (sp[0] + sbi) * ssc);
        sp += 132;
      }
      if (shalf) ltmp[scol_] = P;
      __syncthreads();
      if (!shalf)
        carry[((size_t)bb * NCH2 + c0 + p) * DHID + n0 + scol_] = fmaf(a16, P, ltmp[scol_]);
    }

    const int gm = m0 + p * 32 + row;
    const int col0 = n0 + seg * 16;
    if (MODE == 0) {
      union { unsigned short s[16]; uint4 q[2]; } ub;
      if (n0 < DHID) {
#pragma unroll
        for (int u = 0; u < 4; ++u) {
          float4 v  = *(const float4*)&stg[row * 132 + seg * 16 + u * 4];
          float4 bi = *(const float4*)&bias0[col0 + u * 4];
          float4 sc = *(const float4*)&a_s[DHID + col0 + u * 4];
          ub.s[u * 4 + 0] = f2bf((v.x + bi.x) * sc.x);
          ub.s[u * 4 + 1] = f2bf((v.y + bi.y) * sc.y);
          ub.s[u * 4 + 2] = f2bf((v.z + bi.z) * sc.z);
          ub.s[u * 4 + 3] = f2bf((v.w + bi.w) * sc.w);
        }
        *(uint4*)&u_out[(size_t)gm * DHID + col0]     = ub.q[0];
        *(uint4*)&u_out[(size_t)gm * DHID + col0 + 8] = ub.q[1];
      } else {
        const int c2 = col0 - DHID;
#pragma unroll
        for (int u = 0; u < 4; ++u) {
          float4 v  = *(const float4*)&stg[row * 132 + seg * 16 + u * 4];
          float4 bd = *(const float4*)&bias1[c2 + u * 4];
          ub.s[u * 4 + 0] = f2bf(v.x + bd.x);
          ub.s[u * 4 + 1] = f2bf(v.y + bd.y);
          ub.s[u * 4 + 2] = f2bf(v.z + bd.z);
          ub.s[u * 4 + 3] = f2bf(v.w + bd.w);
        }
        *(uint4*)&dx_buf[(size_t)gm * DOUT + c2]     = ub.q[0];
        *(uint4*)&dx_buf[(size_t)gm * DOUT + c2 + 8] = ub.q[1];
      }
    } else {
#pragma unroll
      for (int u = 0; u < 4; ++u) {
        float4 v  = *(const float4*)&stg[row * 132 + seg * 16 + u * 4];
        float4 bo = *(const float4*)&bias0[col0 + u * 4];
        ushort4 dv = *(const ushort4*)&dx_buf[(size_t)gm * DOUT + col0 + u * 4];
        float4 o;
        o.x = (v.x + bo.x + bf2f(dv.x)) * 0.5f;
        o.y = (v.y + bo.y + bf2f(dv.y)) * 0.5f;
        o.z = (v.z + bo.z + bf2f(dv.z)) * 0.5f;
        o.w = (v.w + bo.w + bf2f(dv.w)) * 0.5f;
        *(float4*)&out[(size_t)gm * DOUT + col0 + u * 4] = o;
      }
    }
  }
}

// ---------- scan kernels ----------
// prefix over chunk-local finals (from GEMM1 epilogue) with 8-deep load batching;
// carry becomes exact chunk-entry state; writes h_last.
__global__ __launch_bounds__(256) void scan_mid(const float* __restrict__ a_s,
                                                const float* __restrict__ h0,
                                                float* __restrict__ carry,
                                                float* __restrict__ h_last) {
  int idx = blockIdx.x * 256 + threadIdx.x;   // B_*DHID = 8192
  int d = idx & (DHID - 1);
  int b = idx >> 10;
  float a = a_s[d];
  float aL = a;
#pragma unroll
  for (int q = 0; q < 5; ++q) aL *= aL;       // a^32
  float st = h0[(size_t)b * DHID + d];
  float* p = &carry[(size_t)b * NCH2 * DHID + d];
  for (int cg = 0; cg < NCH2; cg += 8) {
    float loc[8];
#pragma unroll
    for (int j = 0; j < 8; ++j) loc[j] = p[(size_t)j * DHID];
#pragma unroll
    for (int j = 0; j < 8; ++j) {
      p[(size_t)j * DHID] = st;
      st = fmaf(aL, st, loc[j]);
    }
    p += (size_t)8 * DHID;
  }
  h_last[(size_t)b * DHID + d] = st;
}

// recompute scan from exact entry state; overwrite u with h (bf16)
__global__ __launch_bounds__(256) void scan2(unsigned short* __restrict__ u,
                                             const float* __restrict__ a_s,
                                             const float* __restrict__ carry) {
  int idx = blockIdx.x * 256 + threadIdx.x;
  int d8 = (idx & 127) * 8;
  int c  = (idx >> 7) & (NCH2 - 1);
  int b  = idx >> 14;
  float4 a0 = *(const float4*)&a_s[d8];
  float4 a1 = *(const float4*)&a_s[d8 + 4];
  const float* cp = &carry[((size_t)(b * NCH2 + c)) * DHID + d8];
  float4 e0 = *(const float4*)cp;
  float4 e1 = *(const float4*)(cp + 4);
  float h0_ = e0.x, h1 = e0.y, h2 = e0.z, h3 = e0.w;
  float h4 = e1.x, h5 = e1.y, h6 = e1.z, h7 = e1.w;
  unsigned short* up = u + ((size_t)(b * S_ + c * CH2)) * DHID + d8;
#pragma unroll 4
  for (int t = 0; t < CH2; ++t) {
    ushort4 q0 = *(const ushort4*)up;
    ushort4 q1 = *(const ushort4*)(up + 4);
    h0_ = fmaf(a0.x, h0_, bf2f(q0.x)); h1 = fmaf(a0.y, h1, bf2f(q0.y));
    h2  = fmaf(a0.z, h2,  bf2f(q0.z)); h3 = fmaf(a0.w, h3, bf2f(q0.w));
    h4  = fmaf(a1.x, h4,  bf2f(q1.x)); h5 = fmaf(a1.y, h5, bf2f(q1.y));
    h6  = fmaf(a1.z, h6,  bf2f(q1.z)); h7 = fmaf(a1.w, h7, bf2f(q1.w));
    ushort4 w0, w1;
    w0.x = f2bf(h0_); w0.y = f2bf(h1); w0.z = f2bf(h2); w0.w = f2bf(h3);
    w1.x = f2bf(h4);  w1.y = f2bf(h5); w1.z = f2bf(h6); w1.w = f2bf(h7);
    *(ushort4*)up = w0;
    *(ushort4*)(up + 4) = w1;
    up += DHID;
  }
}

extern "C" void kernel_launch(void* const* d_in, const int* in_sizes, int n_in,
                              void* d_out, int out_size, void* d_ws, size_t ws_size,
                              hipStream_t stream) {
  const float* x    = (const float*)d_in[0];
  const float* h0   = (const float*)d_in[1];
  const float* alog = (const float*)d_in[2];
  const float* Wdx  = (const float*)d_in[3];
  const float* bdx  = (const float*)d_in[4];
  const float* Win  = (const float*)d_in[5];
  const float* bin  = (const float*)d_in[6];
  const float* Wout = (const float*)d_in[7];
  const float* bout = (const float*)d_in[8];

  float* out    = (float*)d_out;
  float* h_last = out + (size_t)M_ * DOUT;

  char* ws = (char*)d_ws;
  unsigned short* xb    = (unsigned short*)(ws);                      // 32 MB
  unsigned short* ubuf  = (unsigned short*)(ws + 33554432ull);        // 64 MB (u -> h in-place)
  unsigned short* dxb   = (unsigned short*)(ws + 100663296ull);       // 32 MB
  unsigned short* wcat  = (unsigned short*)(ws + 134217728ull);       // 1.5 MB
  unsigned short* woutt = (unsigned short*)(ws + 135790592ull);       // 1 MB
  float*          a_s   = (float*)(ws + 136839168ull);                // 8 KB
  float*          carry = (float*)(ws + 136847360ull);                // 4 MB (live during GEMM1)

  // 1 launch: all weight transposes + gate precompute + x->bf16
  prep_all<<<5124 + (M_ * DIN / 8) / 256, 256, 0, stream>>>(
      alog, Win, Wdx, Wout, x, a_s, wcat, woutt, xb);

  // GEMM1 (+fused chunk-local scan): u=(x@W_in+b_in)*s, dx=x@W_dx+b_dx, carry[b][c][d]
  gemm_bt<DIN, 0, 12><<<dim3(NCAT / 128, M_ / 128), 256, 0, stream>>>(
      xb, wcat, a_s, bin, bdx, ubuf, dxb, nullptr, carry);

  // prefix over chunks + h_last
  scan_mid<<<(B_ * DHID) / 256, 256, 0, stream>>>(a_s, h0, carry, h_last);
  // full scan from exact entry states, u -> h in place
  scan2   <<<(B_ * NCH2 * (DHID / 8)) / 256, 256, 0, stream>>>(ubuf, a_s, carry);

  // GEMM2: out = (dx + h@W_out + b_out)/2
  gemm_bt<DHID, 1, 4><<<dim3(DOUT / 128, M_ / 128), 256, 0, stream>>>(
      ubuf, woutt, a_s, bout, nullptr, nullptr, dxb, out, nullptr);
}